// Round 9
// baseline (195.495 us; speedup 1.0000x reference)
//
#include <hip/hip_runtime.h>
#include <cstdint>

#define BDIM 8192
#define DDIM 128
#define JS 32

// ws layout (bytes)
#define ZH_OFF 0
#define ZL_OFF (2 * 1024 * 1024)
#define RL_OFF (4 * 1024 * 1024)
#define CNT_OFF (RL_OFF + BDIM * 4)          // int cnt
#define IC_OFF (CNT_OFF + 64)                // int ic[64] per-i-tile counters
#define DC_OFF (IC_OFF + 256)                // int done-counter
#define GS_OFF (DC_OFF + 64)                 // float gsum, gcnt
#define P_OFF (RL_OFF + 65536)               // float2 P2[BDIM][JS] = 2 MB

typedef __attribute__((ext_vector_type(8))) short bf16x8;   // 8 bf16 = 4 VGPRs
typedef __attribute__((ext_vector_type(4))) float f32x4;

__device__ __forceinline__ short f2bf(float f) {            // RTN-even fp32->bf16
  unsigned u = __float_as_uint(f);
  unsigned r = (u + 0x7fffu + ((u >> 16) & 1u)) >> 16;
  return (short)r;
}
__device__ __forceinline__ float bf2f(short h) {
  return __uint_as_float(((unsigned)(unsigned short)h) << 16);
}
__device__ __forceinline__ void gload_lds16(const void* g, void* l) {
  __builtin_amdgcn_global_load_lds(
      (const __attribute__((address_space(1))) unsigned int*)g,
      (__attribute__((address_space(3))) unsigned int*)l, 16, 0, 0);
}

// Fragment-tiled Z layout (shorts): element (row,k) at
//   (row>>4)*2048 + (k>>5)*512 + ((k>>3)&3)*128 + (row&15)*8 + (k&7)
// -> one MFMA fragment (16 rows x 8 k) = contiguous 1 KB per wave; a
//    (j16,kc) unit is 1 KB linear in BOTH global and LDS (direct DMA copy).

// Kernel 1: blocks 0..511 normalize + bf16 hi/lo split (tiled layout);
// block 512 compacts censor==1 rows (prefix scan), zeroes finalize state.
__global__ __launch_bounds__(256) void ck_prep(
    const float* __restrict__ emb, const int* __restrict__ censor,
    short* __restrict__ ZhT, short* __restrict__ ZlT,
    int* __restrict__ rowlist, int* __restrict__ cnt,
    int* __restrict__ ic, int* __restrict__ dc, float* __restrict__ gsc,
    float* __restrict__ out)
{
  __shared__ float zl[16][132];
  __shared__ float pr[16][16];
  __shared__ float inv[16];
  __shared__ int wtot[4], woff[4];

  const int t = threadIdx.x;
  if (blockIdx.x == 512) {               // ---- compact branch ----
    if (t < 64) ic[t] = 0;               // zero finalize state (ws poisoned)
    if (t == 64) dc[0] = 0;
    if (t == 65) { gsc[0] = 0.f; gsc[1] = 0.f; }
    const int lane = t & 63, wv = t >> 6;
    const int4* c4 = (const int4*)(censor + t * 32);
    unsigned fm = 0;
#pragma unroll
    for (int q = 0; q < 8; ++q) {
      const int4 v = c4[q];
      fm |= (unsigned)(v.x == 1) << (q * 4 + 0);
      fm |= (unsigned)(v.y == 1) << (q * 4 + 1);
      fm |= (unsigned)(v.z == 1) << (q * 4 + 2);
      fm |= (unsigned)(v.w == 1) << (q * 4 + 3);
    }
    const int loc = __popc(fm);
    int sc = loc;                         // inclusive wave scan
#pragma unroll
    for (int m = 1; m < 64; m <<= 1) {
      const int u = __shfl_up(sc, m, 64);
      if (lane >= m) sc += u;
    }
    if (lane == 63) wtot[wv] = sc;
    __syncthreads();
    if (t == 0) {
      int run = 0;
#pragma unroll
      for (int i = 0; i < 4; ++i) { woff[i] = run; run += wtot[i]; }
    }
    __syncthreads();
    int off = woff[wv] + sc - loc;
    for (int u = 0; u < 32; ++u)
      if ((fm >> u) & 1) rowlist[off++] = t * 32 + u;
    if (t == 255) {
      cnt[0] = off;
      if (off == 0) out[0] = 0.f;         // fallback: no uncensored rows
    }
    return;
  }

  // ---- normalize branch: one 16-row tile per block ----
  const int R = blockIdx.x;
  const int r16 = t >> 4, seg = t & 15;
  const float4* src = (const float4*)(emb + (size_t)(R * 16 + r16) * DDIM + seg * 8);
  const float4 v0 = src[0], v1 = src[1];
  float* zr = &zl[r16][seg * 8];
  zr[0] = v0.x; zr[1] = v0.y; zr[2] = v0.z; zr[3] = v0.w;
  zr[4] = v1.x; zr[5] = v1.y; zr[6] = v1.z; zr[7] = v1.w;
  pr[r16][seg] = v0.x * v0.x + v0.y * v0.y + v0.z * v0.z + v0.w * v0.w +
                 v1.x * v1.x + v1.y * v1.y + v1.z * v1.z + v1.w * v1.w;
  __syncthreads();
  if (t < 16) {
    float ss = 0.f;
#pragma unroll
    for (int s = 0; s < 16; ++s) ss += pr[t][s];
    inv[t] = 1.0f / fmaxf(sqrtf(ss), 1e-12f);   // F.normalize semantics
  }
  __syncthreads();
  const int kc = t >> 6, hf = (t >> 4) & 3, rw = t & 15;
  const float iv = inv[rw];
  const float* zs = &zl[rw][(kc * 4 + hf) * 8];
  short hs[8], ls[8];
#pragma unroll
  for (int j = 0; j < 8; ++j) {
    const float z = zs[j] * iv;
    const short h = f2bf(z);
    hs[j] = h;
    ls[j] = f2bf(z - bf2f(h));
  }
  const int dst = R * 2048 + t * 8;
  *(bf16x8*)(ZhT + dst) = *(const bf16x8*)hs;
  *(bf16x8*)(ZlT + dst) = *(const bf16x8*)ls;
}

// Kernel 2: MFMA sim + masked exp-sums + MERGED FINALIZE. Structure is the
// measured-best R5 kernel (a=2, 64KB dbuf, 4 st-steps, js-MAJOR mapping, all
// loop-invariant loads hoisted). New: the last-arriving js-block per i-tile
// combines that tile's 32 split sums (identical summation order to the old
// ck_fin) and the last-done i-tile writes the output -- removes the ck_fin
// launch + inter-kernel gap (~8-10 us of the ~20 us non-fill overhead).
__global__ __launch_bounds__(256, 2) void ck_main(
    const short* __restrict__ ZhT, const short* __restrict__ ZlT,
    const int* __restrict__ rowlist, const int* __restrict__ cntp,
    const int* __restrict__ times, float2* __restrict__ P2,
    int* __restrict__ ic, int* __restrict__ dc, float* __restrict__ gsc,
    float* __restrict__ out)
{
  __shared__ __align__(16) char lds[65536];
  __shared__ int lastFlag;
  const int cnt = *cntp;
  if (cnt == 0) return;
  const int t = threadIdx.x;
  const int nIT = (cnt + 127) >> 7;        // active i-tiles
  const int b = blockIdx.x;
  const int js = b / nIT;                  // j-split (256 j)  -- js-major order
  const int it = b - js * nIT;             // i-tile (128 rows, compacted)
  if (js >= JS) return;
  const int lane = t & 63;
  const int w = t >> 6;
  const int half = lane >> 4;
  const int ll = lane & 15;
  const int jR0 = js * 16;                 // base j16 unit

  // A-frag rows (A rows m = ll), a = 0..1 -> wave covers 32 i-rows
  int rbase[2];
#pragma unroll
  for (int a = 0; a < 2; ++a) {
    int c = it * 128 + w * 32 + a * 16 + ll;
    if (c >= cnt) c = cnt - 1;             // duplicate valid row; masked at store
    const int r = rowlist[c];
    rbase[a] = (r >> 4) * 2048 + (r & 15) * 8;
  }

  // prologue: stage st=0 into buffer 0 (wave w copies 1KB chunks w*8..w*8+7)
  // issued FIRST so DMA overlaps the register-prefill below
  {
    const int c0 = w * 8;
#pragma unroll
    for (int u = 0; u < 8; ++u) {
      const int c = c0 + u, cp = c & 15;
      const short* src = (c < 16) ? ZhT : ZlT;
      const short* gp = src + (size_t)(jR0 + (cp >> 2)) * 2048 + (cp & 3) * 512 + lane * 8;
      gload_lds16(gp, lds + ((c < 16) ? 0 : 16384) + cp * 1024);
    }
  }

  bf16x8 ah[2][4], al[2][4];               // A-hi + A-lo resident (64 VGPR)
#pragma unroll
  for (int a = 0; a < 2; ++a)
#pragma unroll
    for (int kc = 0; kc < 4; ++kc) {
      ah[a][kc] = *(const bf16x8*)(ZhT + rbase[a] + kc * 512 + half * 128);
      al[a][kc] = *(const bf16x8*)(ZlT + rbase[a] + kc * 512 + half * 128);
    }

  // packed per-(a,r) meta for C/D rows (row = half*4 + r):
  // meta = (ti+364)<<16 | gi ; invalid: gi=0xFFFF, taP=50000 (tests false)
  int meta[2][4];
#pragma unroll
  for (int a = 0; a < 2; ++a)
#pragma unroll
    for (int r = 0; r < 4; ++r) {
      const int idx = it * 128 + w * 32 + a * 16 + half * 4 + r;
      const bool vi = idx < cnt;
      const int gi = rowlist[vi ? idx : 0];
      const int taP = vi ? (times[gi] + 364) : 50000;
      meta[a][r] = (taP << 16) | (vi ? gi : 0xFFFF);
    }

  // preload ALL epilogue times[] (4 st x 4 bb) -> 16 VGPR, off critical path
  int tJall[4][4];
#pragma unroll
  for (int st = 0; st < 4; ++st)
#pragma unroll
    for (int bb = 0; bb < 4; ++bb)
      tJall[st][bb] = times[js * 256 + st * 64 + bb * 16 + ll];

  float sd[2][4] = {{0.f}}, sn[2][4] = {{0.f}};

  for (int st = 0; st < 4; ++st) {
    __syncthreads();                       // buf[st&1] resident (drains vmcnt)
    if (st < 3) {                          // stage st+1 into other buffer;
      const int pB = ((st + 1) & 1) * 32768;   // drained by NEXT barrier
      const int c0 = w * 8;
#pragma unroll
      for (int u = 0; u < 8; ++u) {
        const int c = c0 + u, cp = c & 15;
        const short* src = (c < 16) ? ZhT : ZlT;
        const short* gp = src + (size_t)(jR0 + (st + 1) * 4 + (cp >> 2)) * 2048 + (cp & 3) * 512 + lane * 8;
        gload_lds16(gp, lds + pB + ((c < 16) ? 0 : 16384) + cp * 1024);
      }
    }

    const char* L = lds + (st & 1) * 32768;
    f32x4 acc[2][4];
#pragma unroll
    for (int a = 0; a < 2; ++a)
#pragma unroll
      for (int bb = 0; bb < 4; ++bb) acc[a][bb] = (f32x4){0.f, 0.f, 0.f, 0.f};

#pragma unroll
    for (int kc = 0; kc < 4; ++kc) {
#pragma unroll
      for (int bb = 0; bb < 4; ++bb) {     // b-major: one B hi/lo pair live
        const bf16x8 bhv = *(const bf16x8*)(L + bb * 4096 + kc * 1024 + lane * 16);
        const bf16x8 blv = *(const bf16x8*)(L + 16384 + bb * 4096 + kc * 1024 + lane * 16);
        acc[0][bb] = __builtin_amdgcn_mfma_f32_16x16x32_bf16(ah[0][kc], bhv, acc[0][bb], 0, 0, 0);
        acc[1][bb] = __builtin_amdgcn_mfma_f32_16x16x32_bf16(ah[1][kc], bhv, acc[1][bb], 0, 0, 0);
        acc[0][bb] = __builtin_amdgcn_mfma_f32_16x16x32_bf16(ah[0][kc], blv, acc[0][bb], 0, 0, 0);
        acc[1][bb] = __builtin_amdgcn_mfma_f32_16x16x32_bf16(ah[1][kc], blv, acc[1][bb], 0, 0, 0);
        acc[0][bb] = __builtin_amdgcn_mfma_f32_16x16x32_bf16(al[0][kc], bhv, acc[0][bb], 0, 0, 0);
        acc[1][bb] = __builtin_amdgcn_mfma_f32_16x16x32_bf16(al[1][kc], bhv, acc[1][bb], 0, 0, 0);
      }
    }

    // epilogue for this 64-j step: exp2-direct fixed-offset exp-sums:
    // exp(10*s - 10) == exp2(s*K2 - K2), K2 = 10*log2(e)  (one fmaf + v_exp)
    const float K2 = 14.426950408889634f;
    const int jb = js * 256 + st * 64;
#pragma unroll
    for (int a = 0; a < 2; ++a)
#pragma unroll
      for (int r = 0; r < 4; ++r) {
        const int m_ = meta[a][r];
        const int gi = m_ & 0xFFFF;
        const unsigned taP = ((unsigned)m_) >> 16;
        float d = 0.f, n = 0.f;
#pragma unroll
        for (int bb = 0; bb < 4; ++bb) {
          const int jgb = jb + bb * 16 + ll;
          float pv = __builtin_amdgcn_exp2f(fmaf(acc[a][bb][r], K2, -K2));
          pv = (gi == jgb) ? 0.f : pv;                 // diagonal mask
          d += pv;
          // |ti-tj|<365  <=>  (u32)(ti+364-tj) <= 728
          n += ((unsigned)(taP - (unsigned)tJall[st][bb]) <= 728u) ? pv : 0.f;
        }
        sd[a][r] += d;
        sn[a][r] += n;
      }
  }

  // reduce over ll (lane bits 0..3); one float2 store per valid row
#pragma unroll
  for (int a = 0; a < 2; ++a)
#pragma unroll
    for (int r = 0; r < 4; ++r) {
      float d = sd[a][r], n = sn[a][r];
#pragma unroll
      for (int m = 1; m <= 8; m <<= 1) {
        d += __shfl_xor(d, m, 64);
        n += __shfl_xor(n, m, 64);
      }
      const int idx = it * 128 + w * 32 + a * 16 + half * 4 + r;
      if (ll == 0 && idx < cnt) P2[(size_t)idx * JS + js] = make_float2(d, n);
    }

  // ---- merged finalize: last js-block of this i-tile combines it ----
  __threadfence();                         // release this block's P2 stores
  __syncthreads();
  if (t == 0) lastFlag = (atomicAdd(&ic[it], 1) == JS - 1);
  __syncthreads();
  if (!lastFlag) return;                   // uniform per block
  __threadfence();                         // acquire other blocks' P2 stores

  const int r0 = it * 128;
  const int rows = min(128, cnt - r0);
  float ls = 0.f, lc = 0.f;
  if (t < rows) {
    const float4* p = (const float4*)(P2 + (size_t)(r0 + t) * JS);  // 256 B
    float d = 0.f, n = 0.f;
#pragma unroll
    for (int u = 0; u < 16; ++u) {         // identical order to old ck_fin
      const float4 v = p[u];
      d += v.x + v.z;
      n += v.y + v.w;
    }
    if (n > 0.f) { ls = logf(d) - logf(n); lc = 1.f; }
  }
  float* s1 = (float*)lds;                 // LDS free after last barrier
  float* s2 = s1 + 256;
  s1[t] = ls; s2[t] = lc;
  __syncthreads();
  for (int s = 128; s > 0; s >>= 1) {
    if (t < s) { s1[t] += s1[t + s]; s2[t] += s2[t + s]; }
    __syncthreads();
  }
  if (t == 0) {
    atomicAdd(&gsc[0], s1[0]);
    atomicAdd(&gsc[1], s2[0]);
    __threadfence();                       // release partials before signaling
    if (atomicAdd(dc, 1) == nIT - 1) {     // last-done i-tile writes output
      const float s_ = atomicAdd(&gsc[0], 0.f);   // coherent reads
      const float c_ = atomicAdd(&gsc[1], 0.f);
      out[0] = (c_ > 0.f) ? s_ / fmaxf(c_, 1.f) : 0.f;
    }
  }
}

extern "C" void kernel_launch(void* const* d_in, const int* in_sizes, int n_in,
                              void* d_out, int out_size, void* d_ws, size_t ws_size,
                              hipStream_t stream) {
  const float* emb  = (const float*)d_in[0];
  const int* times  = (const int*)d_in[1];
  const int* censor = (const int*)d_in[2];
  float* out = (float*)d_out;

  char* ws = (char*)d_ws;
  short* ZhT    = (short*)(ws + ZH_OFF);
  short* ZlT    = (short*)(ws + ZL_OFF);
  int* rowlist  = (int*)(ws + RL_OFF);
  int* cntp     = (int*)(ws + CNT_OFF);
  int* ic       = (int*)(ws + IC_OFF);
  int* dc       = (int*)(ws + DC_OFF);
  float* gsc    = (float*)(ws + GS_OFF);
  float2* P2    = (float2*)(ws + P_OFF);

  ck_prep<<<513, 256, 0, stream>>>(emb, censor, ZhT, ZlT, rowlist, cntp, ic, dc, gsc, out);
  ck_main<<<64 * JS, 256, 0, stream>>>(ZhT, ZlT, rowlist, cntp, times, P2, ic, dc, gsc, out);
}

// Round 10
// 108.364 us; speedup vs baseline: 1.8041x; 1.8041x over previous
//
#include <hip/hip_runtime.h>
#include <cstdint>

#define BDIM 8192
#define DDIM 128
#define JS 32

// ws layout (bytes)
#define ZH_OFF 0
#define ZL_OFF (2 * 1024 * 1024)
#define RL_OFF (4 * 1024 * 1024)
#define CNT_OFF (RL_OFF + BDIM * 4)          // int cnt
#define FC_OFF (CNT_OFF + 64)                // int fin_counter
#define P_OFF (RL_OFF + 65536)               // float2 P2[BDIM][JS] = 2 MB
#define PART_OFF (P_OFF + BDIM * JS * 8)     // float2 part[32]

typedef __attribute__((ext_vector_type(8))) short bf16x8;   // 8 bf16 = 4 VGPRs
typedef __attribute__((ext_vector_type(4))) float f32x4;

__device__ __forceinline__ short f2bf(float f) {            // RTN-even fp32->bf16
  unsigned u = __float_as_uint(f);
  unsigned r = (u + 0x7fffu + ((u >> 16) & 1u)) >> 16;
  return (short)r;
}
__device__ __forceinline__ float bf2f(short h) {
  return __uint_as_float(((unsigned)(unsigned short)h) << 16);
}
__device__ __forceinline__ void gload_lds16(const void* g, void* l) {
  __builtin_amdgcn_global_load_lds(
      (const __attribute__((address_space(1))) unsigned int*)g,
      (__attribute__((address_space(3))) unsigned int*)l, 16, 0, 0);
}

// Fragment-tiled Z layout (shorts): element (row,k) at
//   (row>>4)*2048 + (k>>5)*512 + ((k>>3)&3)*128 + (row&15)*8 + (k&7)
// -> one MFMA fragment (16 rows x 8 k) = contiguous 1 KB per wave; a
//    (j16,kc) unit is 1 KB linear in BOTH global and LDS (direct DMA copy).

// Kernel 1: blocks 0..511 normalize + bf16 hi/lo split (tiled layout);
// block 512 compacts censor==1 rows (prefix scan) and zeroes fin_counter.
__global__ __launch_bounds__(256) void ck_prep(
    const float* __restrict__ emb, const int* __restrict__ censor,
    short* __restrict__ ZhT, short* __restrict__ ZlT,
    int* __restrict__ rowlist, int* __restrict__ cnt, int* __restrict__ fc)
{
  __shared__ float zl[16][132];
  __shared__ float pr[16][16];
  __shared__ float inv[16];
  __shared__ int wtot[4], woff[4];

  const int t = threadIdx.x;
  if (blockIdx.x == 512) {               // ---- compact branch ----
    const int lane = t & 63, wv = t >> 6;
    const int4* c4 = (const int4*)(censor + t * 32);
    unsigned fm = 0;
#pragma unroll
    for (int q = 0; q < 8; ++q) {
      const int4 v = c4[q];
      fm |= (unsigned)(v.x == 1) << (q * 4 + 0);
      fm |= (unsigned)(v.y == 1) << (q * 4 + 1);
      fm |= (unsigned)(v.z == 1) << (q * 4 + 2);
      fm |= (unsigned)(v.w == 1) << (q * 4 + 3);
    }
    const int loc = __popc(fm);
    int sc = loc;                         // inclusive wave scan
#pragma unroll
    for (int m = 1; m < 64; m <<= 1) {
      const int u = __shfl_up(sc, m, 64);
      if (lane >= m) sc += u;
    }
    if (lane == 63) wtot[wv] = sc;
    __syncthreads();
    if (t == 0) {
      int run = 0;
#pragma unroll
      for (int i = 0; i < 4; ++i) { woff[i] = run; run += wtot[i]; }
      fc[0] = 0;                          // zero finalize counter (ws poisoned)
    }
    __syncthreads();
    int off = woff[wv] + sc - loc;
    for (int u = 0; u < 32; ++u)
      if ((fm >> u) & 1) rowlist[off++] = t * 32 + u;
    if (t == 255) cnt[0] = off;
    return;
  }

  // ---- normalize branch: one 16-row tile per block ----
  const int R = blockIdx.x;
  const int r16 = t >> 4, seg = t & 15;
  const float4* src = (const float4*)(emb + (size_t)(R * 16 + r16) * DDIM + seg * 8);
  const float4 v0 = src[0], v1 = src[1];
  float* zr = &zl[r16][seg * 8];
  zr[0] = v0.x; zr[1] = v0.y; zr[2] = v0.z; zr[3] = v0.w;
  zr[4] = v1.x; zr[5] = v1.y; zr[6] = v1.z; zr[7] = v1.w;
  pr[r16][seg] = v0.x * v0.x + v0.y * v0.y + v0.z * v0.z + v0.w * v0.w +
                 v1.x * v1.x + v1.y * v1.y + v1.z * v1.z + v1.w * v1.w;
  __syncthreads();
  if (t < 16) {
    float ss = 0.f;
#pragma unroll
    for (int s = 0; s < 16; ++s) ss += pr[t][s];
    inv[t] = 1.0f / fmaxf(sqrtf(ss), 1e-12f);   // F.normalize semantics
  }
  __syncthreads();
  const int kc = t >> 6, hf = (t >> 4) & 3, rw = t & 15;
  const float iv = inv[rw];
  const float* zs = &zl[rw][(kc * 4 + hf) * 8];
  short hs[8], ls[8];
#pragma unroll
  for (int j = 0; j < 8; ++j) {
    const float z = zs[j] * iv;
    const short h = f2bf(z);
    hs[j] = h;
    ls[j] = f2bf(z - bf2f(h));
  }
  const int dst = R * 2048 + t * 8;
  *(bf16x8*)(ZhT + dst) = *(const bf16x8*)hs;
  *(bf16x8*)(ZlT + dst) = *(const bf16x8*)ls;
}

// Kernel 2: MFMA sim + masked exp-sums. Block = 128 i (4 waves x 32) x 256 j
// (4 st-steps of 64). Wave tile 32i x 64j (a=2).
// ALL loop-invariant global loads hoisted out of the st loop: A-hi (ah),
// A-lo (al), and the 16 times[] values (tJall). The st loop touches only
// LDS + registers; no L2-latency loads sit on the MFMA critical path.
// NOTE (R9 lesson): do NOT add device-scope fences/atomics to this kernel's
// tail -- it forces the compiler to rematerialize the hoisted state into the
// loop (VGPR drops to 128) and the whole loop slows ~3.5x.
// Block mapping js-MAJOR: co-resident blocks share one 256 KB B-panel (L2).
// B hi/lo staged to 2x32KB LDS dbuf via global_load_lds; one barrier per
// st-step, next step's loads issued right after it.
__global__ __launch_bounds__(256, 2) void ck_main(
    const short* __restrict__ ZhT, const short* __restrict__ ZlT,
    const int* __restrict__ rowlist, const int* __restrict__ cntp,
    const int* __restrict__ times, float2* __restrict__ P2)
{
  __shared__ __align__(16) char lds[65536];
  const int cnt = *cntp;
  if (cnt == 0) return;
  const int t = threadIdx.x;
  const int nIT = (cnt + 127) >> 7;        // active i-tiles
  const int b = blockIdx.x;
  const int js = b / nIT;                  // j-split (256 j)  -- js-major order
  const int it = b - js * nIT;             // i-tile (128 rows, compacted)
  if (js >= JS) return;
  const int lane = t & 63;
  const int w = t >> 6;
  const int half = lane >> 4;
  const int ll = lane & 15;
  const int jR0 = js * 16;                 // base j16 unit

  // A-frag rows (A rows m = ll), a = 0..1 -> wave covers 32 i-rows
  int rbase[2];
#pragma unroll
  for (int a = 0; a < 2; ++a) {
    int c = it * 128 + w * 32 + a * 16 + ll;
    if (c >= cnt) c = cnt - 1;             // duplicate valid row; masked at store
    const int r = rowlist[c];
    rbase[a] = (r >> 4) * 2048 + (r & 15) * 8;
  }

  // prologue: stage st=0 into buffer 0 (wave w copies 1KB chunks w*8..w*8+7)
  // issued FIRST so DMA overlaps the register-prefill below
  {
    const int c0 = w * 8;
#pragma unroll
    for (int u = 0; u < 8; ++u) {
      const int c = c0 + u, cp = c & 15;
      const short* src = (c < 16) ? ZhT : ZlT;
      const short* gp = src + (size_t)(jR0 + (cp >> 2)) * 2048 + (cp & 3) * 512 + lane * 8;
      gload_lds16(gp, lds + ((c < 16) ? 0 : 16384) + cp * 1024);
    }
  }

  bf16x8 ah[2][4], al[2][4];               // A-hi + A-lo resident (64 VGPR)
#pragma unroll
  for (int a = 0; a < 2; ++a)
#pragma unroll
    for (int kc = 0; kc < 4; ++kc) {
      ah[a][kc] = *(const bf16x8*)(ZhT + rbase[a] + kc * 512 + half * 128);
      al[a][kc] = *(const bf16x8*)(ZlT + rbase[a] + kc * 512 + half * 128);
    }

  // packed per-(a,r) meta for C/D rows (row = half*4 + r):
  // meta = (ti+364)<<16 | gi ; invalid: gi=0xFFFF, taP=50000 (tests false)
  int meta[2][4];
#pragma unroll
  for (int a = 0; a < 2; ++a)
#pragma unroll
    for (int r = 0; r < 4; ++r) {
      const int idx = it * 128 + w * 32 + a * 16 + half * 4 + r;
      const bool vi = idx < cnt;
      const int gi = rowlist[vi ? idx : 0];
      const int taP = vi ? (times[gi] + 364) : 50000;
      meta[a][r] = (taP << 16) | (vi ? gi : 0xFFFF);
    }

  // preload ALL epilogue times[] (4 st x 4 bb) -> 16 VGPR, off critical path
  int tJall[4][4];
#pragma unroll
  for (int st = 0; st < 4; ++st)
#pragma unroll
    for (int bb = 0; bb < 4; ++bb)
      tJall[st][bb] = times[js * 256 + st * 64 + bb * 16 + ll];

  float sd[2][4] = {{0.f}}, sn[2][4] = {{0.f}};

  for (int st = 0; st < 4; ++st) {
    __syncthreads();                       // buf[st&1] resident (drains vmcnt)
    if (st < 3) {                          // stage st+1 into other buffer;
      const int pB = ((st + 1) & 1) * 32768;   // drained by NEXT barrier
      const int c0 = w * 8;
#pragma unroll
      for (int u = 0; u < 8; ++u) {
        const int c = c0 + u, cp = c & 15;
        const short* src = (c < 16) ? ZhT : ZlT;
        const short* gp = src + (size_t)(jR0 + (st + 1) * 4 + (cp >> 2)) * 2048 + (cp & 3) * 512 + lane * 8;
        gload_lds16(gp, lds + pB + ((c < 16) ? 0 : 16384) + cp * 1024);
      }
    }

    const char* L = lds + (st & 1) * 32768;
    f32x4 acc[2][4];
#pragma unroll
    for (int a = 0; a < 2; ++a)
#pragma unroll
      for (int bb = 0; bb < 4; ++bb) acc[a][bb] = (f32x4){0.f, 0.f, 0.f, 0.f};

#pragma unroll
    for (int kc = 0; kc < 4; ++kc) {
#pragma unroll
      for (int bb = 0; bb < 4; ++bb) {     // b-major: one B hi/lo pair live
        const bf16x8 bhv = *(const bf16x8*)(L + bb * 4096 + kc * 1024 + lane * 16);
        const bf16x8 blv = *(const bf16x8*)(L + 16384 + bb * 4096 + kc * 1024 + lane * 16);
        acc[0][bb] = __builtin_amdgcn_mfma_f32_16x16x32_bf16(ah[0][kc], bhv, acc[0][bb], 0, 0, 0);
        acc[1][bb] = __builtin_amdgcn_mfma_f32_16x16x32_bf16(ah[1][kc], bhv, acc[1][bb], 0, 0, 0);
        acc[0][bb] = __builtin_amdgcn_mfma_f32_16x16x32_bf16(ah[0][kc], blv, acc[0][bb], 0, 0, 0);
        acc[1][bb] = __builtin_amdgcn_mfma_f32_16x16x32_bf16(ah[1][kc], blv, acc[1][bb], 0, 0, 0);
        acc[0][bb] = __builtin_amdgcn_mfma_f32_16x16x32_bf16(al[0][kc], bhv, acc[0][bb], 0, 0, 0);
        acc[1][bb] = __builtin_amdgcn_mfma_f32_16x16x32_bf16(al[1][kc], bhv, acc[1][bb], 0, 0, 0);
      }
    }

    // epilogue for this 64-j step: exp2-direct fixed-offset exp-sums:
    // exp(10*s - 10) == exp2(s*K2 - K2), K2 = 10*log2(e)  (one fmaf + v_exp)
    const float K2 = 14.426950408889634f;
    const int jb = js * 256 + st * 64;
#pragma unroll
    for (int a = 0; a < 2; ++a)
#pragma unroll
      for (int r = 0; r < 4; ++r) {
        const int m_ = meta[a][r];
        const int gi = m_ & 0xFFFF;
        const unsigned taP = ((unsigned)m_) >> 16;
        float d = 0.f, n = 0.f;
#pragma unroll
        for (int bb = 0; bb < 4; ++bb) {
          const int jgb = jb + bb * 16 + ll;
          float pv = __builtin_amdgcn_exp2f(fmaf(acc[a][bb][r], K2, -K2));
          pv = (gi == jgb) ? 0.f : pv;                 // diagonal mask
          d += pv;
          // |ti-tj|<365  <=>  (u32)(ti+364-tj) <= 728
          n += ((unsigned)(taP - (unsigned)tJall[st][bb]) <= 728u) ? pv : 0.f;
        }
        sd[a][r] += d;
        sn[a][r] += n;
      }
  }

  // reduce over ll (lane bits 0..3); one float2 store per valid row
#pragma unroll
  for (int a = 0; a < 2; ++a)
#pragma unroll
    for (int r = 0; r < 4; ++r) {
      float d = sd[a][r], n = sn[a][r];
#pragma unroll
      for (int m = 1; m <= 8; m <<= 1) {
        d += __shfl_xor(d, m, 64);
        n += __shfl_xor(n, m, 64);
      }
      const int idx = it * 128 + w * 32 + a * 16 + half * 4 + r;
      if (ll == 0 && idx < cnt) P2[(size_t)idx * JS + js] = make_float2(d, n);
    }
}

// Kernel 3: combine 32 splits + log-ratio; last block (threadfence + counter)
// reduces the 32 block partials and writes out. Single dispatch.
__global__ __launch_bounds__(256) void ck_fin(
    const float2* __restrict__ P2, const int* __restrict__ cntp,
    float2* __restrict__ part, int* __restrict__ fc, float* __restrict__ out)
{
  const int cnt = *cntp;
  const int t = threadIdx.x;
  const int idx = blockIdx.x * 256 + t;
  float lsum = 0.f, lcnt = 0.f;
  if (idx < cnt) {
    const float4* p = (const float4*)(P2 + (size_t)idx * JS);  // 256 B
    float d = 0.f, n = 0.f;
#pragma unroll
    for (int u = 0; u < 16; ++u) {
      const float4 v = p[u];
      d += v.x + v.z;
      n += v.y + v.w;
    }
    if (n > 0.f) { lsum = logf(d) - logf(n); lcnt = 1.f; }
  }
  __shared__ float s1[256], s2[256];
  __shared__ int amLast;
  s1[t] = lsum; s2[t] = lcnt;
  __syncthreads();
  for (int s = 128; s > 0; s >>= 1) {
    if (t < s) { s1[t] += s1[t + s]; s2[t] += s2[t + s]; }
    __syncthreads();
  }
  if (t == 0) {
    part[blockIdx.x] = make_float2(s1[0], s2[0]);
    __threadfence();                        // release partial before signaling
    amLast = (atomicAdd(fc, 1) == gridDim.x - 1);
  }
  __syncthreads();
  if (amLast) {
    __threadfence();                        // acquire others' partials
    float s = 0.f, c = 0.f;
    if (t < 32) { const float2 v = part[t]; s = v.x; c = v.y; }
    if (t < 64) {
#pragma unroll
      for (int m = 1; m < 64; m <<= 1) {
        s += __shfl_xor(s, m, 64);
        c += __shfl_xor(c, m, 64);
      }
      if (t == 0) out[0] = (c > 0.f) ? s / fmaxf(c, 1.f) : 0.f;
    }
  }
}

extern "C" void kernel_launch(void* const* d_in, const int* in_sizes, int n_in,
                              void* d_out, int out_size, void* d_ws, size_t ws_size,
                              hipStream_t stream) {
  const float* emb  = (const float*)d_in[0];
  const int* times  = (const int*)d_in[1];
  const int* censor = (const int*)d_in[2];
  float* out = (float*)d_out;

  char* ws = (char*)d_ws;
  short* ZhT    = (short*)(ws + ZH_OFF);
  short* ZlT    = (short*)(ws + ZL_OFF);
  int* rowlist  = (int*)(ws + RL_OFF);
  int* cntp     = (int*)(ws + CNT_OFF);
  int* fc       = (int*)(ws + FC_OFF);
  float2* P2    = (float2*)(ws + P_OFF);
  float2* part  = (float2*)(ws + PART_OFF);

  ck_prep<<<513, 256, 0, stream>>>(emb, censor, ZhT, ZlT, rowlist, cntp, fc);
  ck_main<<<64 * JS, 256, 0, stream>>>(ZhT, ZlT, rowlist, cntp, times, P2);
  ck_fin<<<32, 256, 0, stream>>>(P2, cntp, part, fc, out);
}